// Round 1
// baseline (286.419 us; speedup 1.0000x reference)
//
#include <hip/hip_runtime.h>
#include <math.h>

constexpr int B = 128, N = 512, HID = 512, NH = 8, DH = 64;

// ---------------------------------------------------------------------------
// K1: query = w_seed_w*seed + w_seed_b; q = w_q @ query;
//     qk[h][j] = (1/sqrt(DH)) * sum_d q[h*64+d] * w_v[(h*64+d)*HID + j]
// Re-parallelized: grid 64 (h = bid>>3, jc = bid&7), block 256 (was 64).
// q-phase: wave-per-row coalesced dot; qk-phase: d-range split across waves.
// ---------------------------------------------------------------------------
__global__ __launch_bounds__(256) void k1_qk(
    const float* __restrict__ w_q, const float* __restrict__ w_v,
    const float* __restrict__ w_sw, const float* __restrict__ w_sb,
    const float* __restrict__ seed, float* __restrict__ qk)
{
    __shared__ __align__(16) float query_s[HID];
    __shared__ float q_s[DH];
    __shared__ float red_s[4][64];
    const int t  = threadIdx.x;
    const int l  = t & 63;
    const int w  = t >> 6;
    const int h  = blockIdx.x >> 3;
    const int jc = blockIdx.x & 7;
    const float sv = seed[0];
    {
        const int j = t * 2;
        query_s[j]     = w_sw[j]     * sv + w_sb[j];
        query_s[j + 1] = w_sw[j + 1] * sv + w_sb[j + 1];
    }
    __syncthreads();
    {   // hoist this lane's query slice once (avoids per-row LDS conflicts)
        const float4 qa = *(const float4*)&query_s[l * 8];
        const float4 qb = *(const float4*)&query_s[l * 8 + 4];
        for (int i = 0; i < 16; ++i) {
            const int r = w * 16 + i;
            const float* row = w_q + (size_t)(h * DH + r) * HID + l * 8;
            const float4 a = *(const float4*)row;
            const float4 bx = *(const float4*)(row + 4);
            float acc = a.x * qa.x + a.y * qa.y + a.z * qa.z + a.w * qa.w
                      + bx.x * qb.x + bx.y * qb.y + bx.z * qb.z + bx.w * qb.w;
            #pragma unroll
            for (int off = 32; off; off >>= 1) acc += __shfl_xor(acc, off, 64);
            if (l == 0) q_s[r] = acc;
        }
    }
    __syncthreads();
    {
        const int j = jc * 64 + l;
        float acc = 0.f;
        #pragma unroll
        for (int i = 0; i < 16; ++i) {
            const int d = w * 16 + i;
            acc += q_s[d] * w_v[(size_t)(h * DH + d) * HID + j];
        }
        red_s[w][l] = acc;
    }
    __syncthreads();
    if (t < 64) {
        const float v = red_s[0][t] + red_s[1][t] + red_s[2][t] + red_s[3][t];
        qk[h * HID + jc * 64 + t] = v * 0.125f;   // fold 1/sqrt(64)
    }
}

// ---------------------------------------------------------------------------
// KP: FUSED logits + chunk-local online softmax + chunk MAC. SINGLE h pass.
// grid B*8 (b = bid>>3, 64-row chunk c = bid&7), block 256 (4 waves).
// Per 16-row sub-tile: [A] stage rows to LDS + wave-per-row logit dots
// (R5/R7-proven shuffle tree, also writes raw e to e_t for KA);
// [B] per-head online (m,s) update + p = exp(e - m) to LDS;
// [C] col-partitioned MAC from LDS (thread = 1 head x 4 col-quads,
// i-stride 512B -> conflict-free ds_read_b128, 2-lane head-dup = broadcast).
// Emits unnormalized ctxp[b][c][hh][:] + stats (m_c, s_c). Empty chunks
// zero-fill ctxp (poison-safe for kd1) and write (m,s)=(-3e38, 0).
// ---------------------------------------------------------------------------
__global__ __launch_bounds__(256) void kp_fused(
    const float* __restrict__ hbuf, const int* __restrict__ lengths,
    const float* __restrict__ qk, float* __restrict__ e_t,
    float* __restrict__ ctxp, float2* __restrict__ stats)
{
    __shared__ __align__(16) float rowbuf[16][HID];  // 32 KB
    __shared__ float e_s[16][NH];
    __shared__ float p_s[16][NH];
    __shared__ float f_s[NH];

    const int t = threadIdx.x;
    const int l = t & 63;
    const int w = t >> 6;
    const int b = blockIdx.x >> 3;
    const int c = blockIdx.x & 7;
    const int n0 = c * 64;
    const int len = lengths[b];
    const int bc = b * 8 + c;

    if (n0 >= len) {                  // block-uniform: zero-fill + stats, exit
        if (t < NH) stats[bc * NH + t] = make_float2(-3.0e38f, 0.f);
        float4* cz = (float4*)(ctxp + (size_t)bc * NH * HID);
        const float4 z = {0.f, 0.f, 0.f, 0.f};
        #pragma unroll
        for (int i = 0; i < 4; ++i) cz[t * 4 + i] = z;
        return;
    }

    float4 qlo[NH], qhi[NH];
    #pragma unroll
    for (int hh = 0; hh < NH; ++hh) {
        qlo[hh] = *(const float4*)&qk[hh * HID + l * 4];
        qhi[hh] = *(const float4*)&qk[hh * HID + 256 + l * 4];
    }

    const float* hb = hbuf + (size_t)b * N * HID;
    const int hh_out = ((l & 1) << 2) | (l & 2) | ((l >> 2) & 1);
    const int hh_m = t >> 5;                 // MAC head (0..7)
    const int cg   = t & 31;                 // MAC col group
    const int li   = l & 31;                 // stats row lane
    const int hh_s = w + ((l >> 5) << 2);    // stats head: lanes 0-31 -> w, 32-63 -> w+4

    float m_run = -3.0e38f, s_run = 0.f;
    float4 acc0 = {0,0,0,0}, acc1 = {0,0,0,0}, acc2 = {0,0,0,0}, acc3 = {0,0,0,0};

    #pragma unroll 1
    for (int sc = 0; sc < 4; ++sc) {
        const int rn0 = n0 + sc * 16;
        const int nv = min(16, len - rn0);   // valid rows this sub (may be <= 0)

        // ---- phase A: stage + logits (wave-uniform guards) ----
        #pragma unroll
        for (int k = 0; k < 4; ++k) {
            const int rl = w + 4 * k;
            if (rl < nv) {
                const int rn = rn0 + rl;
                const float* row = hb + (size_t)rn * HID;
                const float4 h0 = *(const float4*)(row + l * 4);
                const float4 h1 = *(const float4*)(row + 256 + l * 4);
                *(float4*)&rowbuf[rl][l * 4] = h0;
                *(float4*)&rowbuf[rl][256 + l * 4] = h1;
                float v[NH];
                #pragma unroll
                for (int hh = 0; hh < NH; ++hh)
                    v[hh] = h0.x * qlo[hh].x + h0.y * qlo[hh].y
                          + h0.z * qlo[hh].z + h0.w * qlo[hh].w
                          + h1.x * qhi[hh].x + h1.y * qhi[hh].y
                          + h1.z * qhi[hh].z + h1.w * qhi[hh].w;
                #pragma unroll
                for (int i = 0; i < 4; ++i) {
                    const float ax = __shfl_xor(v[i], 1, 64);
                    const float bx = __shfl_xor(v[i + 4], 1, 64);
                    v[i] = (l & 1) ? (v[i + 4] + bx) : (v[i] + ax);
                }
                #pragma unroll
                for (int i = 0; i < 2; ++i) {
                    const float ax = __shfl_xor(v[i], 2, 64);
                    const float bx = __shfl_xor(v[i + 2], 2, 64);
                    v[i] = (l & 2) ? (v[i + 2] + bx) : (v[i] + ax);
                }
                {
                    const float ax = __shfl_xor(v[0], 4, 64);
                    const float bx = __shfl_xor(v[1], 4, 64);
                    v[0] = (l & 4) ? (v[1] + bx) : (v[0] + ax);
                }
                v[0] += __shfl_xor(v[0], 8, 64);
                v[0] += __shfl_xor(v[0], 16, 64);
                v[0] += __shfl_xor(v[0], 32, 64);
                if (l < 8) {
                    e_t[((size_t)b * N + rn) * NH + hh_out] = v[0];
                    e_s[rl][hh_out] = v[0];
                }
            }
        }
        __syncthreads();

        // ---- phase B: per-head online (m,s); xor masks 1/2/4/8 stay in 16-groups
        {
            const float e = (li < nv) ? e_s[li][hh_s] : -3.0e38f;
            float m_sub = e;
            m_sub = fmaxf(m_sub, __shfl_xor(m_sub, 1, 64));
            m_sub = fmaxf(m_sub, __shfl_xor(m_sub, 2, 64));
            m_sub = fmaxf(m_sub, __shfl_xor(m_sub, 4, 64));
            m_sub = fmaxf(m_sub, __shfl_xor(m_sub, 8, 64));
            const float m_new = fmaxf(m_run, m_sub);
            const float p = (li < nv) ? __expf(e - m_new) : 0.f;
            float s_sub = p;
            s_sub += __shfl_xor(s_sub, 1, 64);
            s_sub += __shfl_xor(s_sub, 2, 64);
            s_sub += __shfl_xor(s_sub, 4, 64);
            s_sub += __shfl_xor(s_sub, 8, 64);
            const float f = __expf(m_run - m_new);  // -3e38 - real -> 0; 0 diff -> 1
            s_run = s_run * f + s_sub;
            m_run = m_new;
            if (li < nv) p_s[li][hh_s] = p;
            if (li == 0) f_s[hh_s] = f;
        }
        __syncthreads();

        // ---- phase C: rescale + MAC from LDS ----
        {
            const float f = f_s[hh_m];
            acc0.x *= f; acc0.y *= f; acc0.z *= f; acc0.w *= f;
            acc1.x *= f; acc1.y *= f; acc1.z *= f; acc1.w *= f;
            acc2.x *= f; acc2.y *= f; acc2.z *= f; acc2.w *= f;
            acc3.x *= f; acc3.y *= f; acc3.z *= f; acc3.w *= f;
            for (int rl = 0; rl < nv; ++rl) {
                const float p = p_s[rl][hh_m];
                const float4 r0 = *(const float4*)&rowbuf[rl][cg * 4];
                const float4 r1 = *(const float4*)&rowbuf[rl][128 + cg * 4];
                const float4 r2 = *(const float4*)&rowbuf[rl][256 + cg * 4];
                const float4 r3 = *(const float4*)&rowbuf[rl][384 + cg * 4];
                acc0.x = fmaf(p, r0.x, acc0.x); acc0.y = fmaf(p, r0.y, acc0.y);
                acc0.z = fmaf(p, r0.z, acc0.z); acc0.w = fmaf(p, r0.w, acc0.w);
                acc1.x = fmaf(p, r1.x, acc1.x); acc1.y = fmaf(p, r1.y, acc1.y);
                acc1.z = fmaf(p, r1.z, acc1.z); acc1.w = fmaf(p, r1.w, acc1.w);
                acc2.x = fmaf(p, r2.x, acc2.x); acc2.y = fmaf(p, r2.y, acc2.y);
                acc2.z = fmaf(p, r2.z, acc2.z); acc2.w = fmaf(p, r2.w, acc2.w);
                acc3.x = fmaf(p, r3.x, acc3.x); acc3.y = fmaf(p, r3.y, acc3.y);
                acc3.z = fmaf(p, r3.z, acc3.z); acc3.w = fmaf(p, r3.w, acc3.w);
            }
        }
        __syncthreads();   // protect rowbuf/e_s for next sub
    }

    if (li == 0) stats[bc * NH + hh_s] = make_float2(m_run, s_run);
    float* cp = ctxp + ((size_t)bc * NH + hh_m) * HID + cg * 4;
    *(float4*)(cp + 0)   = acc0;
    *(float4*)(cp + 128) = acc1;
    *(float4*)(cp + 256) = acc2;
    *(float4*)(cp + 384) = acc3;
}

// ---------------------------------------------------------------------------
// KA: alpha[b][hh][n] = (n < len) ? exp(e_t[b][n][hh] - M[b,hh]) / S[b,hh] : 0
// grid B, block 256. Coalesced e_t read, LDS transpose, coalesced alpha write.
// Invalid-n e_t is workspace poison -> masked by select (never multiplied).
// ---------------------------------------------------------------------------
__global__ __launch_bounds__(256) void ka_alpha(
    const int* __restrict__ lengths, const float* __restrict__ e_t,
    const float2* __restrict__ stats, float* __restrict__ alpha)
{
    __shared__ float m_l[NH], rs_l[NH];
    __shared__ float al_s[NH][N];                    // 16 KB
    const int t = threadIdx.x;
    const int b = blockIdx.x;
    const int len = lengths[b];
    if (t < NH) {
        float M = -3.0e38f;
        #pragma unroll
        for (int cc = 0; cc < 8; ++cc)
            M = fmaxf(M, stats[(b * 8 + cc) * NH + t].x);
        float S = 0.f;
        #pragma unroll
        for (int cc = 0; cc < 8; ++cc) {
            const float2 ms = stats[(b * 8 + cc) * NH + t];
            S += ms.y * __expf(ms.x - M);            // empty chunk: 0 * 0
        }
        m_l[t] = M;
        rs_l[t] = 1.f / S;                           // len >= 1 -> S > 0
    }
    __syncthreads();
    const float* eb = e_t + (size_t)b * N * NH;
    #pragma unroll
    for (int k = 0; k < 16; ++k) {
        const int flat = k * 256 + t;                // [n][hh] flat
        const int n = flat >> 3;
        const int hh = flat & 7;
        const float e = eb[flat];
        al_s[hh][n] = (n < len) ? __expf(e - m_l[hh]) * rs_l[hh] : 0.f;
    }
    __syncthreads();
    float* ab = alpha + (size_t)b * NH * N;
    const float* af = (const float*)al_s;            // [hh][n] flat == alpha layout
    #pragma unroll
    for (int k = 0; k < 16; ++k) {
        const int flat = k * 256 + t;
        ab[flat] = af[flat];
    }
}

// ---------------------------------------------------------------------------
// KD1: oh[b][p] = < sum_c w_c(b,c,ht) * ctxp[b][c][ht][:], w_v[p][:] >
// where w_c = exp(m_c - M)/S (global-softmax chunk weights, computed in-block
// from stats). grid 64 (ht = bid&7, bt = bid>>3), block 256.
// ---------------------------------------------------------------------------
__global__ __launch_bounds__(256) void kd1_oh(
    const float* __restrict__ ctxp, const float2* __restrict__ stats,
    const float* __restrict__ w_v, float* __restrict__ oh)
{
    __shared__ __align__(16) float ctx_s[16][HID];   // 32 KB
    __shared__ float w_s[16][8];
    const int t  = threadIdx.x;
    const int ht = blockIdx.x & 7;
    const int bt = blockIdx.x >> 3;

    if (t < 16) {
        const int bb = bt * 16 + t;
        float m_c[8], s_c[8];
        float M = -3.0e38f;
        #pragma unroll
        for (int cc = 0; cc < 8; ++cc) {
            const float2 ms = stats[(bb * 8 + cc) * NH + ht];
            m_c[cc] = ms.x; s_c[cc] = ms.y;
            M = fmaxf(M, ms.x);
        }
        float S = 0.f;
        #pragma unroll
        for (int cc = 0; cc < 8; ++cc) S += s_c[cc] * __expf(m_c[cc] - M);
        const float rS = 1.f / S;
        #pragma unroll
        for (int cc = 0; cc < 8; ++cc) w_s[t][cc] = __expf(m_c[cc] - M) * rS;
    }
    __syncthreads();

    for (int idx = t; idx < 16 * 128; idx += 256) {
        const int bb_l = idx >> 7;
        const int j4   = idx & 127;
        const int bb   = bt * 16 + bb_l;
        const float* p0 = ctxp + ((size_t)(bb * 8) * NH + ht) * HID + j4 * 4;
        float4 s = {0.f, 0.f, 0.f, 0.f};
        #pragma unroll
        for (int cc = 0; cc < 8; ++cc) {
            const float wcc = w_s[bb_l][cc];         // broadcast
            const float4 v = *(const float4*)(p0 + (size_t)cc * NH * HID);
            s.x = fmaf(wcc, v.x, s.x); s.y = fmaf(wcc, v.y, s.y);
            s.z = fmaf(wcc, v.z, s.z); s.w = fmaf(wcc, v.w, s.w);
        }
        *(float4*)&ctx_s[bb_l][j4 * 4] = s;
    }
    __syncthreads();

    const int d  = t & 63;
    const int bs = t >> 6;
    const int p  = ht * 64 + d;
    const float* wrow = w_v + (size_t)p * HID;
    float acc[4] = {0.f, 0.f, 0.f, 0.f};
    for (int j = 0; j < HID; j += 4) {
        const float4 wv = *(const float4*)(wrow + j);
        #pragma unroll
        for (int bi = 0; bi < 4; ++bi) {
            const float4 cv = *(const float4*)&ctx_s[bs * 4 + bi][j];  // broadcast
            acc[bi] += wv.x * cv.x + wv.y * cv.y + wv.z * cv.z + wv.w * cv.w;
        }
    }
    #pragma unroll
    for (int bi = 0; bi < 4; ++bi) {
        const int bb = bt * 16 + bs * 4 + bi;
        oh[(size_t)bb * HID + p] = acc[bi];
    }
}

// ---------------------------------------------------------------------------
// KD2: out[b][i] = <oh[b][:], w_o[i][:]>  (unchanged)
// ---------------------------------------------------------------------------
__global__ __launch_bounds__(256) void kd2_out(
    const float* __restrict__ oh, const float* __restrict__ w_o,
    float* __restrict__ out)
{
    __shared__ __align__(16) float oh_s[16][HID];    // 32 KB
    const int t  = threadIdx.x;
    const int it = blockIdx.x & 7;
    const int bt = blockIdx.x >> 3;

    for (int idx = t; idx < 16 * 128; idx += 256) {
        const int bb_l = idx >> 7;
        const int j4   = idx & 127;
        const int bb   = bt * 16 + bb_l;
        *(float4*)&oh_s[bb_l][j4 * 4] =
            *(const float4*)&oh[(size_t)bb * HID + j4 * 4];
    }
    __syncthreads();

    const int d  = t & 63;
    const int bs = t >> 6;
    const int i  = it * 64 + d;
    const float* wrow = w_o + (size_t)i * HID;
    float acc[4] = {0.f, 0.f, 0.f, 0.f};
    for (int j = 0; j < HID; j += 4) {
        const float4 wv = *(const float4*)(wrow + j);
        #pragma unroll
        for (int bi = 0; bi < 4; ++bi) {
            const float4 ov = *(const float4*)&oh_s[bs * 4 + bi][j];   // broadcast
            acc[bi] += wv.x * ov.x + wv.y * ov.y + wv.z * ov.z + wv.w * ov.w;
        }
    }
    #pragma unroll
    for (int bi = 0; bi < 4; ++bi) {
        const int bb = bt * 16 + bs * 4 + bi;
        out[(size_t)bb * HID + i] = acc[bi];
    }
}

// ---------------------------------------------------------------------------
extern "C" void kernel_launch(void* const* d_in, const int* in_sizes, int n_in,
                              void* d_out, int out_size, void* d_ws, size_t ws_size,
                              hipStream_t stream) {
    const float* h     = (const float*)d_in[0];
    const int*   lens  = (const int*)  d_in[1];
    const float* w_q   = (const float*)d_in[2];
    // d_in[3] = w_k: dead compute in the reference, intentionally unused
    const float* w_v   = (const float*)d_in[4];
    const float* w_o   = (const float*)d_in[5];
    const float* w_sw  = (const float*)d_in[6];
    const float* w_sb  = (const float*)d_in[7];
    const float* seed  = (const float*)d_in[8];

    float* out   = (float*)d_out;            // [B, HID]
    float* alpha = out + (size_t)B * HID;    // [B, NH, N, 1]

    // ws (floats): qk[4096] | e_t[B*N*NH] | ctxp[B*8*NH*HID] | stats[B*8*NH*2] | oh[65536]
    float* ws    = (float*)d_ws;
    float* qk    = ws;
    float* e_t   = qk + NH * HID;
    float* ctxp  = e_t + (size_t)B * N * NH;
    float* statf = ctxp + (size_t)B * 8 * NH * HID;
    float* oh    = statf + (size_t)B * 8 * NH * 2;

    hipLaunchKernelGGL(k1_qk,    dim3(64),    dim3(256), 0, stream,
                       w_q, w_v, w_sw, w_sb, seed, qk);
    hipLaunchKernelGGL(kp_fused, dim3(B * 8), dim3(256), 0, stream,
                       h, lens, qk, e_t, ctxp, (float2*)statf);
    hipLaunchKernelGGL(ka_alpha, dim3(B),     dim3(256), 0, stream,
                       lens, e_t, (const float2*)statf, alpha);
    hipLaunchKernelGGL(kd1_oh,   dim3(64),    dim3(256), 0, stream,
                       ctxp, (const float2*)statf, w_v, oh);
    hipLaunchKernelGGL(kd2_out,  dim3(64),    dim3(256), 0, stream,
                       oh, w_o, out);
}

// Round 2
// 284.104 us; speedup vs baseline: 1.0081x; 1.0081x over previous
//
#include <hip/hip_runtime.h>
#include <math.h>

constexpr int B = 128, N = 512, HID = 512, NH = 8, DH = 64;
constexpr int CH = 4;            // chunks per batch
constexpr int CROWS = N / CH;    // 128 rows per chunk

// ---------------------------------------------------------------------------
// K1: query = w_seed_w*seed + w_seed_b; q = w_q @ query;
//     qk[h][j] = (1/sqrt(DH)) * sum_d q[h*64+d] * w_v[(h*64+d)*HID + j]
// grid 64 (h = bid>>3, jc = bid&7), block 256.
// ---------------------------------------------------------------------------
__global__ __launch_bounds__(256) void k1_qk(
    const float* __restrict__ w_q, const float* __restrict__ w_v,
    const float* __restrict__ w_sw, const float* __restrict__ w_sb,
    const float* __restrict__ seed, float* __restrict__ qk)
{
    __shared__ __align__(16) float query_s[HID];
    __shared__ float q_s[DH];
    __shared__ float red_s[4][64];
    const int t  = threadIdx.x;
    const int l  = t & 63;
    const int w  = t >> 6;
    const int h  = blockIdx.x >> 3;
    const int jc = blockIdx.x & 7;
    const float sv = seed[0];
    {
        const int j = t * 2;
        query_s[j]     = w_sw[j]     * sv + w_sb[j];
        query_s[j + 1] = w_sw[j + 1] * sv + w_sb[j + 1];
    }
    __syncthreads();
    {
        const float4 qa = *(const float4*)&query_s[l * 8];
        const float4 qb = *(const float4*)&query_s[l * 8 + 4];
        for (int i = 0; i < 16; ++i) {
            const int r = w * 16 + i;
            const float* row = w_q + (size_t)(h * DH + r) * HID + l * 8;
            const float4 a = *(const float4*)row;
            const float4 bx = *(const float4*)(row + 4);
            float acc = a.x * qa.x + a.y * qa.y + a.z * qa.z + a.w * qa.w
                      + bx.x * qb.x + bx.y * qb.y + bx.z * qb.z + bx.w * qb.w;
            #pragma unroll
            for (int off = 32; off; off >>= 1) acc += __shfl_xor(acc, off, 64);
            if (l == 0) q_s[r] = acc;
        }
    }
    __syncthreads();
    {
        const int j = jc * 64 + l;
        float acc = 0.f;
        #pragma unroll
        for (int i = 0; i < 16; ++i) {
            const int d = w * 16 + i;
            acc += q_s[d] * w_v[(size_t)(h * DH + d) * HID + j];
        }
        red_s[w][l] = acc;
    }
    __syncthreads();
    if (t < 64) {
        const float v = red_s[0][t] + red_s[1][t] + red_s[2][t] + red_s[3][t];
        qk[h * HID + jc * 64 + t] = v * 0.125f;   // fold 1/sqrt(64)
    }
}

// ---------------------------------------------------------------------------
// KF: FLASH fused logits + online softmax + MAC, SINGLE touch per h row.
// grid B*CH (b = bid>>2, 128-row chunk c = bid&3), block 256 (4 waves).
// Main loop (NO barriers, NO LDS): wave owns row n; row lives in regs
// (h0,h1 = 8 floats/lane); shuffle-tree -> e[8 heads] on all lanes via
// involution broadcast; per-head online (m,s) update (wave-uniform bump
// branch); p[hh]*row FMA'd into 8x2 float4 lane accumulators.
// Epilogue: 4 wave-partials combined via 64KB LDS with exp(m_w-m_c)
// factors; emits unnormalized ctxp[b][c][hh][:] + (m_c, s_c) stats.
// Raw e written to e_t (lanes 0..7, 32B/row) for KA's alpha output.
// Empty chunks: zero ctxp slice (poison-safe) + stats (-3e38, 0).
// ---------------------------------------------------------------------------
__global__ __launch_bounds__(256, 2) void kf_flash(
    const float* __restrict__ hbuf, const int* __restrict__ lengths,
    const float* __restrict__ qk, float* __restrict__ e_t,
    float* __restrict__ ctxp, float2* __restrict__ stats)
{
    __shared__ __align__(16) float part[4][NH][HID];   // 64 KB
    __shared__ float2 ms_s[4][NH];
    __shared__ float fct[4][NH];
    __shared__ float mc_s[NH];

    const int t = threadIdx.x;
    const int l = t & 63;
    const int w = t >> 6;
    const int b = blockIdx.x >> 2;
    const int c = blockIdx.x & 3;
    const int n0 = c * CROWS;
    const int len = lengths[b];
    const int bc = b * CH + c;

    if (n0 >= len) {                  // block-uniform: zero-fill + stats, exit
        if (t < NH) stats[bc * NH + t] = make_float2(-3.0e38f, 0.f);
        float4* cz = (float4*)(ctxp + (size_t)bc * NH * HID);
        const float4 z = {0.f, 0.f, 0.f, 0.f};
        #pragma unroll
        for (int i = 0; i < 4; ++i) cz[i * 256 + t] = z;
        return;
    }

    float4 qlo[NH], qhi[NH];
    #pragma unroll
    for (int hh = 0; hh < NH; ++hh) {
        qlo[hh] = *(const float4*)&qk[hh * HID + l * 4];
        qhi[hh] = *(const float4*)&qk[hh * HID + 256 + l * 4];
    }

    const float* hb = hbuf + (size_t)b * N * HID;
    const int nmax = min(n0 + CROWS, len);
    const int hh_out = ((l & 1) << 2) | (l & 2) | ((l >> 2) & 1);

    float m_run[NH], s_run[NH];
    float4 acc0[NH], acc1[NH];
    #pragma unroll
    for (int hh = 0; hh < NH; ++hh) {
        m_run[hh] = -3.0e38f; s_run[hh] = 0.f;
        acc0[hh] = make_float4(0.f, 0.f, 0.f, 0.f);
        acc1[hh] = make_float4(0.f, 0.f, 0.f, 0.f);
    }

    for (int n = n0 + w; n < nmax; n += 4) {
        const float* row = hb + (size_t)n * HID;
        const float4 h0 = *(const float4*)(row + l * 4);        // 1KB/wave
        const float4 h1 = *(const float4*)(row + 256 + l * 4);  // 1KB/wave
        float v[NH];
        #pragma unroll
        for (int hh = 0; hh < NH; ++hh)
            v[hh] = h0.x * qlo[hh].x + h0.y * qlo[hh].y
                  + h0.z * qlo[hh].z + h0.w * qlo[hh].w
                  + h1.x * qhi[hh].x + h1.y * qhi[hh].y
                  + h1.z * qhi[hh].z + h1.w * qhi[hh].w;
        #pragma unroll
        for (int i = 0; i < 4; ++i) {
            const float ax = __shfl_xor(v[i], 1, 64);
            const float bx = __shfl_xor(v[i + 4], 1, 64);
            v[i] = (l & 1) ? (v[i + 4] + bx) : (v[i] + ax);
        }
        #pragma unroll
        for (int i = 0; i < 2; ++i) {
            const float ax = __shfl_xor(v[i], 2, 64);
            const float bx = __shfl_xor(v[i + 2], 2, 64);
            v[i] = (l & 2) ? (v[i + 2] + bx) : (v[i] + ax);
        }
        {
            const float ax = __shfl_xor(v[0], 4, 64);
            const float bx = __shfl_xor(v[1], 4, 64);
            v[0] = (l & 4) ? (v[1] + bx) : (v[0] + ax);
        }
        v[0] += __shfl_xor(v[0], 8, 64);
        v[0] += __shfl_xor(v[0], 16, 64);
        v[0] += __shfl_xor(v[0], 32, 64);
        // lane l holds e[hh_out(l&7)]; store raw e for KA
        if (l < 8)
            e_t[((size_t)b * N + n) * NH + hh_out] = v[0];

        // broadcast e[hh] to all lanes (hh_out mapping is an involution)
        float e[NH];
        e[0] = __shfl(v[0], 0, 64); e[1] = __shfl(v[0], 4, 64);
        e[2] = __shfl(v[0], 2, 64); e[3] = __shfl(v[0], 6, 64);
        e[4] = __shfl(v[0], 1, 64); e[5] = __shfl(v[0], 5, 64);
        e[6] = __shfl(v[0], 3, 64); e[7] = __shfl(v[0], 7, 64);

        // online (m,s): wave-uniform bump branch (e lane-replicated)
        bool bump = false;
        #pragma unroll
        for (int hh = 0; hh < NH; ++hh) bump = bump || (e[hh] > m_run[hh]);
        if (bump) {
            #pragma unroll
            for (int hh = 0; hh < NH; ++hh) {
                const float mn = fmaxf(m_run[hh], e[hh]);
                const float f  = __expf(m_run[hh] - mn);   // -3e38 start -> 0
                s_run[hh] *= f;
                acc0[hh].x *= f; acc0[hh].y *= f; acc0[hh].z *= f; acc0[hh].w *= f;
                acc1[hh].x *= f; acc1[hh].y *= f; acc1[hh].z *= f; acc1[hh].w *= f;
                m_run[hh] = mn;
            }
        }
        #pragma unroll
        for (int hh = 0; hh < NH; ++hh) {
            const float p = __expf(e[hh] - m_run[hh]);
            s_run[hh] += p;
            acc0[hh].x = fmaf(p, h0.x, acc0[hh].x);
            acc0[hh].y = fmaf(p, h0.y, acc0[hh].y);
            acc0[hh].z = fmaf(p, h0.z, acc0[hh].z);
            acc0[hh].w = fmaf(p, h0.w, acc0[hh].w);
            acc1[hh].x = fmaf(p, h1.x, acc1[hh].x);
            acc1[hh].y = fmaf(p, h1.y, acc1[hh].y);
            acc1[hh].z = fmaf(p, h1.z, acc1[hh].z);
            acc1[hh].w = fmaf(p, h1.w, acc1[hh].w);
        }
    }

    // ---- epilogue: combine 4 wave partials ----
    #pragma unroll
    for (int hh = 0; hh < NH; ++hh) {
        *(float4*)&part[w][hh][l * 4]       = acc0[hh];
        *(float4*)&part[w][hh][256 + l * 4] = acc1[hh];
    }
    if (l == 0) {
        #pragma unroll
        for (int hh = 0; hh < NH; ++hh)
            ms_s[w][hh] = make_float2(m_run[hh], s_run[hh]);
    }
    __syncthreads();
    if (t < NH) {
        float mc = -3.0e38f;
        #pragma unroll
        for (int ww = 0; ww < 4; ++ww) mc = fmaxf(mc, ms_s[ww][t].x);
        float sc = 0.f;
        #pragma unroll
        for (int ww = 0; ww < 4; ++ww)
            sc += ms_s[ww][t].y * __expf(ms_s[ww][t].x - mc);  // empty wave: 0*0
        stats[bc * NH + t] = make_float2(mc, sc);
        mc_s[t] = mc;
    }
    __syncthreads();
    if (t < 32) {
        const int ww = t >> 3, hh = t & 7;
        fct[ww][hh] = __expf(ms_s[ww][hh].x - mc_s[hh]);       // empty wave -> 0
    }
    __syncthreads();
    {
        const int hh_m = t >> 5;
        const int cg   = t & 31;
        const float f0 = fct[0][hh_m], f1 = fct[1][hh_m];
        const float f2 = fct[2][hh_m], f3 = fct[3][hh_m];
        float* cp = ctxp + ((size_t)bc * NH + hh_m) * HID + cg * 4;
        #pragma unroll
        for (int q = 0; q < 4; ++q) {
            const int col = cg * 4 + q * 128;
            const float4 r0 = *(const float4*)&part[0][hh_m][col];
            const float4 r1 = *(const float4*)&part[1][hh_m][col];
            const float4 r2 = *(const float4*)&part[2][hh_m][col];
            const float4 r3 = *(const float4*)&part[3][hh_m][col];
            float4 o;
            o.x = f0 * r0.x + f1 * r1.x + f2 * r2.x + f3 * r3.x;
            o.y = f0 * r0.y + f1 * r1.y + f2 * r2.y + f3 * r3.y;
            o.z = f0 * r0.z + f1 * r1.z + f2 * r2.z + f3 * r3.z;
            o.w = f0 * r0.w + f1 * r1.w + f2 * r2.w + f3 * r3.w;
            *(float4*)(cp + q * 128) = o;
        }
    }
}

// ---------------------------------------------------------------------------
// KA: alpha[b][hh][n] = (n < len) ? exp(e_t[b][n][hh] - M[b,hh]) / S[b,hh] : 0
// grid B, block 256. Coalesced e_t read, LDS transpose, coalesced alpha write.
// ---------------------------------------------------------------------------
__global__ __launch_bounds__(256) void ka_alpha(
    const int* __restrict__ lengths, const float* __restrict__ e_t,
    const float2* __restrict__ stats, float* __restrict__ alpha)
{
    __shared__ float m_l[NH], rs_l[NH];
    __shared__ float al_s[NH][N];                    // 16 KB
    const int t = threadIdx.x;
    const int b = blockIdx.x;
    const int len = lengths[b];
    if (t < NH) {
        float M = -3.0e38f;
        #pragma unroll
        for (int cc = 0; cc < CH; ++cc)
            M = fmaxf(M, stats[(b * CH + cc) * NH + t].x);
        float S = 0.f;
        #pragma unroll
        for (int cc = 0; cc < CH; ++cc) {
            const float2 ms = stats[(b * CH + cc) * NH + t];
            S += ms.y * __expf(ms.x - M);            // empty chunk: 0 * 0
        }
        m_l[t] = M;
        rs_l[t] = 1.f / S;                           // len >= 1 -> S > 0
    }
    __syncthreads();
    const float* eb = e_t + (size_t)b * N * NH;
    #pragma unroll
    for (int k = 0; k < 16; ++k) {
        const int flat = k * 256 + t;                // [n][hh] flat
        const int n = flat >> 3;
        const int hh = flat & 7;
        const float e = eb[flat];
        al_s[hh][n] = (n < len) ? __expf(e - m_l[hh]) * rs_l[hh] : 0.f;
    }
    __syncthreads();
    float* ab = alpha + (size_t)b * NH * N;
    const float* af = (const float*)al_s;            // [hh][n] flat == alpha layout
    #pragma unroll
    for (int k = 0; k < 16; ++k) {
        const int flat = k * 256 + t;
        ab[flat] = af[flat];
    }
}

// ---------------------------------------------------------------------------
// KD1: oh[b][p] = < sum_c w_c(b,c,ht) * ctxp[b][c][ht][:], w_v[p][:] >
// where w_c = exp(m_c - M)/S. grid 64 (ht = bid&7, bt = bid>>3), block 256.
// ---------------------------------------------------------------------------
__global__ __launch_bounds__(256) void kd1_oh(
    const float* __restrict__ ctxp, const float2* __restrict__ stats,
    const float* __restrict__ w_v, float* __restrict__ oh)
{
    __shared__ __align__(16) float ctx_s[16][HID];   // 32 KB
    __shared__ float w_s[16][CH];
    const int t  = threadIdx.x;
    const int ht = blockIdx.x & 7;
    const int bt = blockIdx.x >> 3;

    if (t < 16) {
        const int bb = bt * 16 + t;
        float m_c[CH], s_c[CH];
        float M = -3.0e38f;
        #pragma unroll
        for (int cc = 0; cc < CH; ++cc) {
            const float2 ms = stats[(bb * CH + cc) * NH + ht];
            m_c[cc] = ms.x; s_c[cc] = ms.y;
            M = fmaxf(M, ms.x);
        }
        float S = 0.f;
        #pragma unroll
        for (int cc = 0; cc < CH; ++cc) S += s_c[cc] * __expf(m_c[cc] - M);
        const float rS = 1.f / S;
        #pragma unroll
        for (int cc = 0; cc < CH; ++cc) w_s[t][cc] = __expf(m_c[cc] - M) * rS;
    }
    __syncthreads();

    for (int idx = t; idx < 16 * 128; idx += 256) {
        const int bb_l = idx >> 7;
        const int j4   = idx & 127;
        const int bb   = bt * 16 + bb_l;
        const float* p0 = ctxp + ((size_t)(bb * CH) * NH + ht) * HID + j4 * 4;
        float4 s = {0.f, 0.f, 0.f, 0.f};
        #pragma unroll
        for (int cc = 0; cc < CH; ++cc) {
            const float wcc = w_s[bb_l][cc];         // broadcast
            const float4 v = *(const float4*)(p0 + (size_t)cc * NH * HID);
            s.x = fmaf(wcc, v.x, s.x); s.y = fmaf(wcc, v.y, s.y);
            s.z = fmaf(wcc, v.z, s.z); s.w = fmaf(wcc, v.w, s.w);
        }
        *(float4*)&ctx_s[bb_l][j4 * 4] = s;
    }
    __syncthreads();

    const int d  = t & 63;
    const int bs = t >> 6;
    const int p  = ht * 64 + d;
    const float* wrow = w_v + (size_t)p * HID;
    float acc[4] = {0.f, 0.f, 0.f, 0.f};
    for (int j = 0; j < HID; j += 4) {
        const float4 wv = *(const float4*)(wrow + j);
        #pragma unroll
        for (int bi = 0; bi < 4; ++bi) {
            const float4 cv = *(const float4*)&ctx_s[bs * 4 + bi][j];  // broadcast
            acc[bi] += wv.x * cv.x + wv.y * cv.y + wv.z * cv.z + wv.w * cv.w;
        }
    }
    #pragma unroll
    for (int bi = 0; bi < 4; ++bi) {
        const int bb = bt * 16 + bs * 4 + bi;
        oh[(size_t)bb * HID + p] = acc[bi];
    }
}

// ---------------------------------------------------------------------------
// KD2: out[b][i] = <oh[b][:], w_o[i][:]>
// ---------------------------------------------------------------------------
__global__ __launch_bounds__(256) void kd2_out(
    const float* __restrict__ oh, const float* __restrict__ w_o,
    float* __restrict__ out)
{
    __shared__ __align__(16) float oh_s[16][HID];    // 32 KB
    const int t  = threadIdx.x;
    const int it = blockIdx.x & 7;
    const int bt = blockIdx.x >> 3;

    for (int idx = t; idx < 16 * 128; idx += 256) {
        const int bb_l = idx >> 7;
        const int j4   = idx & 127;
        const int bb   = bt * 16 + bb_l;
        *(float4*)&oh_s[bb_l][j4 * 4] =
            *(const float4*)&oh[(size_t)bb * HID + j4 * 4];
    }
    __syncthreads();

    const int d  = t & 63;
    const int bs = t >> 6;
    const int i  = it * 64 + d;
    const float* wrow = w_o + (size_t)i * HID;
    float acc[4] = {0.f, 0.f, 0.f, 0.f};
    for (int j = 0; j < HID; j += 4) {
        const float4 wv = *(const float4*)(wrow + j);
        #pragma unroll
        for (int bi = 0; bi < 4; ++bi) {
            const float4 ov = *(const float4*)&oh_s[bs * 4 + bi][j];   // broadcast
            acc[bi] += wv.x * ov.x + wv.y * ov.y + wv.z * ov.z + wv.w * ov.w;
        }
    }
    #pragma unroll
    for (int bi = 0; bi < 4; ++bi) {
        const int bb = bt * 16 + bs * 4 + bi;
        out[(size_t)bb * HID + i] = acc[bi];
    }
}

// ---------------------------------------------------------------------------
extern "C" void kernel_launch(void* const* d_in, const int* in_sizes, int n_in,
                              void* d_out, int out_size, void* d_ws, size_t ws_size,
                              hipStream_t stream) {
    const float* h     = (const float*)d_in[0];
    const int*   lens  = (const int*)  d_in[1];
    const float* w_q   = (const float*)d_in[2];
    // d_in[3] = w_k: dead compute in the reference, intentionally unused
    const float* w_v   = (const float*)d_in[4];
    const float* w_o   = (const float*)d_in[5];
    const float* w_sw  = (const float*)d_in[6];
    const float* w_sb  = (const float*)d_in[7];
    const float* seed  = (const float*)d_in[8];

    float* out   = (float*)d_out;            // [B, HID]
    float* alpha = out + (size_t)B * HID;    // [B, NH, N, 1]

    // ws (floats): qk[4096] | e_t[B*N*NH] | ctxp[B*CH*NH*HID] | stats[B*CH*NH*2] | oh[65536]
    float* ws    = (float*)d_ws;
    float* qk    = ws;
    float* e_t   = qk + NH * HID;
    float* ctxp  = e_t + (size_t)B * N * NH;
    float* statf = ctxp + (size_t)B * CH * NH * HID;
    float* oh    = statf + (size_t)B * CH * NH * 2;

    hipLaunchKernelGGL(k1_qk,    dim3(64),     dim3(256), 0, stream,
                       w_q, w_v, w_sw, w_sb, seed, qk);
    hipLaunchKernelGGL(kf_flash, dim3(B * CH), dim3(256), 0, stream,
                       h, lens, qk, e_t, ctxp, (float2*)statf);
    hipLaunchKernelGGL(ka_alpha, dim3(B),      dim3(256), 0, stream,
                       lens, e_t, (const float2*)statf, alpha);
    hipLaunchKernelGGL(kd1_oh,   dim3(64),     dim3(256), 0, stream,
                       ctxp, (const float2*)statf, w_v, oh);
    hipLaunchKernelGGL(kd2_out,  dim3(64),     dim3(256), 0, stream,
                       oh, w_o, out);
}